// Round 1
// baseline (542.116 us; speedup 1.0000x reference)
//
#include <hip/hip_runtime.h>
#include <stdint.h>

typedef __bf16 bf16x8 __attribute__((ext_vector_type(8)));
typedef float  f32x4  __attribute__((ext_vector_type(4)));

#define N_JOINT 21
#define TB 4
#define REAL_ROWS (N_JOINT * TB)   // 84
#define RPAD 96                    // 6 MFMA M-tiles
#define BATCH 16384

// XOR-swizzle: spread 16B frag slots across banks (rows have power-of-2 byte stride)
__device__ __forceinline__ uint32_t swz(uint32_t byteoff, uint32_t row) {
  return byteoff ^ ((row & 7u) << 4);
}
__device__ __forceinline__ uint16_t f2b(float v) {
  __bf16 b = (__bf16)v;
  return __builtin_bit_cast(uint16_t, b);
}

// (L z)[r][c] for z in LDS with row stride S floats. Graph: 21-joint hand tree.
// L[n][n] = 1 - 1/deg, L[n][m] = -1/deg for neighbors; deg = #nbr + 1 (self loop).
__device__ __forceinline__ float lmix(const float* zb, int S, int r, int c) {
  int e = r / 21;
  int n = r - e * 21;
  const float* rowb = zb + e * 21 * S + c;
  float zv = rowb[n * S];
  float s = zv;
  float invd;
  if (n == 0) {                       // wrist: nbrs 1,5,9,13,17, deg 6
    s += rowb[1 * S] + rowb[5 * S] + rowb[9 * S] + rowb[13 * S] + rowb[17 * S];
    invd = 1.f / 6.f;
  } else {
    int p = (n - 1) & 3;              // position within finger chain
    if (p == 3) {                     // tip: nbr n-1, deg 2
      s += rowb[(n - 1) * S];
      invd = 0.5f;
    } else {                          // base/mid: two nbrs, deg 3
      int left = (p == 0) ? 0 : (n - 1);
      s += rowb[left * S] + rowb[(n + 1) * S];
      invd = 1.f / 3.f;
    }
  }
  return zv - invd * s;
}

__global__ __launch_bounds__(512)
void cheb3_fused(const float* __restrict__ xp,
                 const float* __restrict__ W1p, const float* __restrict__ b1p,
                 const float* __restrict__ W2p, const float* __restrict__ b2p,
                 const float* __restrict__ W3p, const float* __restrict__ b3p,
                 float* __restrict__ outp)
{
  // sA: x bf16 [96][256] (swizzled); reused as zbuf fp32 [84][128] after GEMM1
  // sH: h bf16 [96][128] (swizzled) — A-operand of layers 2,3
  // sB: weight chunk bf16, fragment-friendly layout [n(256)][kc(32)+8 pad]
  __shared__ __align__(16) uint16_t sA[RPAD * 256];
  __shared__ __align__(16) uint16_t sH[RPAD * 128];
  __shared__ __align__(16) uint16_t sB[256 * 40];

  const int tid  = threadIdx.x;
  const int wid  = tid >> 6;          // 0..7
  const int lane = tid & 63;
  const int l15  = lane & 15;
  const int lk   = lane >> 4;         // 0..3
  const int b0   = blockIdx.x * TB;

  char*  sAc  = (char*)sA;
  char*  sHc  = (char*)sH;
  char*  sBc  = (char*)sB;
  float* zbuf = (float*)sA;

  // ---------------- stage x (fp32 -> bf16, swizzled), zero pad rows ----------------
  {
    const float4* xg = (const float4*)(xp + (size_t)b0 * (N_JOINT * 256));
    #pragma unroll
    for (int j = 0; j < 6; ++j) {
      int i = tid + j * 512;
      if (i < (N_JOINT * 256 * TB) / 8) {          // 2688 groups of 8 floats
        float4 v0 = xg[2 * i], v1 = xg[2 * i + 1];
        int f0 = i * 8, r = f0 >> 8, c = f0 & 255;
        bf16x8 o;
        o[0] = (__bf16)v0.x; o[1] = (__bf16)v0.y; o[2] = (__bf16)v0.z; o[3] = (__bf16)v0.w;
        o[4] = (__bf16)v1.x; o[5] = (__bf16)v1.y; o[6] = (__bf16)v1.z; o[7] = (__bf16)v1.w;
        *(bf16x8*)(sAc + swz(r * 512 + c * 2, r)) = o;
      }
    }
    uint4 z16 = make_uint4(0, 0, 0, 0);
    for (int i = tid; i < (12 * 256) / 8; i += 512) {   // sA pad rows 84..95
      int f0 = i * 8, r = 84 + (f0 >> 8), c = f0 & 255;
      *(uint4*)(sAc + swz(r * 512 + c * 2, r)) = z16;
    }
    for (int i = tid; i < (12 * 128) / 8; i += 512) {   // sH pad rows 84..95
      int f0 = i * 8, r = 84 + (f0 >> 7), c = f0 & 127;
      *(uint4*)(sHc + swz(r * 256 + c * 2, r)) = z16;
    }
  }

  const f32x4 zero4 = {0.f, 0.f, 0.f, 0.f};
  f32x4 acc[6][2];

  // ================= LAYER 1: [96][256] @ [256][256] =================
  #pragma unroll
  for (int mt = 0; mt < 6; ++mt)
    #pragma unroll
    for (int nt = 0; nt < 2; ++nt) acc[mt][nt] = zero4;

  for (int ch = 0; ch < 8; ++ch) {
    __syncthreads();                               // WAR on sB (and covers x staging)
    #pragma unroll
    for (int j = 0; j < 16; ++j) {                 // stage Bcat chunk: 256x32 elems
      int i = tid + j * 512;
      int kc = i >> 8, n = i & 255;
      int kg = ch * 32 + kc;
      float v = (n < 128) ? W1p[kg * 128 + n] : W1p[32768 + kg * 128 + (n - 128)];
      sB[n * 40 + kc] = f2b(v);
    }
    __syncthreads();
    const int kbyte = ch * 64 + lk * 16;
    bf16x8 af[6];
    #pragma unroll
    for (int mt = 0; mt < 6; ++mt) {
      int r = mt * 16 + l15;
      af[mt] = *(const bf16x8*)(sAc + swz(r * 512 + kbyte, r));
    }
    #pragma unroll
    for (int nt = 0; nt < 2; ++nt) {
      int n = wid * 32 + nt * 16 + l15;
      bf16x8 bfr = *(const bf16x8*)(sBc + n * 80 + lk * 16);
      #pragma unroll
      for (int mt = 0; mt < 6; ++mt)
        acc[mt][nt] = __builtin_amdgcn_mfma_f32_16x16x32_bf16(af[mt], bfr, acc[mt][nt], 0, 0, 0);
    }
  }
  __syncthreads();   // GEMM1 done; sA (x) now dead -> reuse as zbuf

  // ---- mix 1: z-waves dump z to LDS; u-waves apply L-mix + bias + leaky, write h1 ----
  if (wid >= 4) {
    #pragma unroll
    for (int mt = 0; mt < 6; ++mt)
      #pragma unroll
      for (int nt = 0; nt < 2; ++nt) {
        int c = (wid - 4) * 32 + nt * 16 + l15;
        #pragma unroll
        for (int rg = 0; rg < 4; ++rg) {
          int r = mt * 16 + lk * 4 + rg;
          if (r < REAL_ROWS) zbuf[r * 128 + c] = acc[mt][nt][rg];
        }
      }
  }
  __syncthreads();
  if (wid < 4) {
    #pragma unroll
    for (int mt = 0; mt < 6; ++mt)
      #pragma unroll
      for (int nt = 0; nt < 2; ++nt) {
        int c = wid * 32 + nt * 16 + l15;
        #pragma unroll
        for (int rg = 0; rg < 4; ++rg) {
          int r = mt * 16 + lk * 4 + rg;
          if (r < REAL_ROWS) {
            float h = acc[mt][nt][rg] + lmix(zbuf, 128, r, c) + b1p[c];
            h = (h > 0.f) ? h : 0.01f * h;
            *(uint16_t*)(sHc + swz(r * 256 + c * 2, r)) = f2b(h);
          }
        }
      }
  }
  __syncthreads();

  // ================= LAYER 2: [96][128] @ [128][256] =================
  #pragma unroll
  for (int mt = 0; mt < 6; ++mt)
    #pragma unroll
    for (int nt = 0; nt < 2; ++nt) acc[mt][nt] = zero4;

  for (int ch = 0; ch < 4; ++ch) {
    __syncthreads();
    #pragma unroll
    for (int j = 0; j < 16; ++j) {
      int i = tid + j * 512;
      int kc = i >> 8, n = i & 255;
      int kg = ch * 32 + kc;
      float v = (n < 128) ? W2p[kg * 128 + n] : W2p[16384 + kg * 128 + (n - 128)];
      sB[n * 40 + kc] = f2b(v);
    }
    __syncthreads();
    const int kbyte = ch * 64 + lk * 16;
    bf16x8 af[6];
    #pragma unroll
    for (int mt = 0; mt < 6; ++mt) {
      int r = mt * 16 + l15;
      af[mt] = *(const bf16x8*)(sHc + swz(r * 256 + kbyte, r));
    }
    #pragma unroll
    for (int nt = 0; nt < 2; ++nt) {
      int n = wid * 32 + nt * 16 + l15;
      bf16x8 bfr = *(const bf16x8*)(sBc + n * 80 + lk * 16);
      #pragma unroll
      for (int mt = 0; mt < 6; ++mt)
        acc[mt][nt] = __builtin_amdgcn_mfma_f32_16x16x32_bf16(af[mt], bfr, acc[mt][nt], 0, 0, 0);
    }
  }
  __syncthreads();

  // ---- mix 2 -> h2 into sH (h1 dead) ----
  if (wid >= 4) {
    #pragma unroll
    for (int mt = 0; mt < 6; ++mt)
      #pragma unroll
      for (int nt = 0; nt < 2; ++nt) {
        int c = (wid - 4) * 32 + nt * 16 + l15;
        #pragma unroll
        for (int rg = 0; rg < 4; ++rg) {
          int r = mt * 16 + lk * 4 + rg;
          if (r < REAL_ROWS) zbuf[r * 128 + c] = acc[mt][nt][rg];
        }
      }
  }
  __syncthreads();
  if (wid < 4) {
    #pragma unroll
    for (int mt = 0; mt < 6; ++mt)
      #pragma unroll
      for (int nt = 0; nt < 2; ++nt) {
        int c = wid * 32 + nt * 16 + l15;
        #pragma unroll
        for (int rg = 0; rg < 4; ++rg) {
          int r = mt * 16 + lk * 4 + rg;
          if (r < REAL_ROWS) {
            float h = acc[mt][nt][rg] + lmix(zbuf, 128, r, c) + b2p[c];
            h = (h > 0.f) ? h : 0.01f * h;
            *(uint16_t*)(sHc + swz(r * 256 + c * 2, r)) = f2b(h);
          }
        }
      }
  }
  __syncthreads();

  // ================= LAYER 3: [96][128] @ [128][6->16] =================
  f32x4 acc3 = zero4;
  for (int ch = 0; ch < 4; ++ch) {
    __syncthreads();
    {                                              // stage Bcat3 chunk: 16x32 elems
      int n = tid >> 5, kc = tid & 31;
      int kg = ch * 32 + kc;
      float v = 0.f;
      if (n < 3)      v = W3p[kg * 3 + n];
      else if (n < 6) v = W3p[384 + kg * 3 + (n - 3)];
      sB[n * 40 + kc] = f2b(v);
    }
    __syncthreads();
    if (wid < 6) {
      int r = wid * 16 + l15;
      bf16x8 a3 = *(const bf16x8*)(sHc + swz(r * 256 + ch * 64 + lk * 16, r));
      bf16x8 b3 = *(const bf16x8*)(sBc + l15 * 80 + lk * 16);
      acc3 = __builtin_amdgcn_mfma_f32_16x16x32_bf16(a3, b3, acc3, 0, 0, 0);
    }
  }
  __syncthreads();                                 // GEMM3 done; zbuf region free

  // z3 (cols 3..5) -> LDS, stride-4 rows
  if (wid < 6 && l15 >= 3 && l15 < 6) {
    #pragma unroll
    for (int rg = 0; rg < 4; ++rg) {
      int r = wid * 16 + lk * 4 + rg;
      if (r < REAL_ROWS) zbuf[r * 4 + (l15 - 3)] = acc3[rg];
    }
  }
  __syncthreads();
  // u3 (cols 0..2) + L z3 + b3 -> global out
  if (wid < 6 && l15 < 3) {
    #pragma unroll
    for (int rg = 0; rg < 4; ++rg) {
      int r = wid * 16 + lk * 4 + rg;
      if (r < REAL_ROWS) {
        float v = acc3[rg] + lmix(zbuf, 4, r, l15) + b3p[l15];
        int e = r / 21;
        int n = r - e * 21;
        outp[((size_t)(b0 + e) * 21 + n) * 3 + l15] = v;
      }
    }
  }
}

extern "C" void kernel_launch(void* const* d_in, const int* in_sizes, int n_in,
                              void* d_out, int out_size, void* d_ws, size_t ws_size,
                              hipStream_t stream) {
  const float* xp  = (const float*)d_in[0];
  const float* W1p = (const float*)d_in[1];
  const float* b1p = (const float*)d_in[2];
  const float* W2p = (const float*)d_in[3];
  const float* b2p = (const float*)d_in[4];
  const float* W3p = (const float*)d_in[5];
  const float* b3p = (const float*)d_in[6];
  float* outp = (float*)d_out;

  dim3 grid(BATCH / TB);   // 4096
  dim3 block(512);
  hipLaunchKernelGGL(cheb3_fused, grid, block, 0, stream,
                     xp, W1p, b1p, W2p, b2p, W3p, b3p, outp);
}